// Round 11
// baseline (6875.924 us; speedup 1.0000x reference)
//
#include <hip/hip_runtime.h>
#include <hip/hip_bf16.h>

#define B_SZ 1024
#define T_SZ 128
#define D_SZ 256
#define H_SZ 512
#define NBLK 512
#define AUXS 0x1   // CPol SC0 on LOADS: bypass stale L1, read XCD-local L2.
                   // STORES are plain write-back (allocate local L2) — state
                   // producer/consumer are co-located on one XCD by mapping.

typedef __attribute__((ext_vector_type(8))) short short8;
typedef __attribute__((ext_vector_type(4))) float f32x4;

__device__ inline f32x4 mfma16(short8 a, short8 b, f32x4 c) {
  return __builtin_amdgcn_mfma_f32_16x16x32_bf16(a, b, c, 0, 0, 0);
}

// plain write-back store: lands in writer XCD's L2 (L1 is write-through),
// retired by vmcnt(0) before the strip barrier signals.
__device__ inline void st_bf16(__hip_bfloat16* p, float v) {
  union { __hip_bfloat16 b; unsigned short u; } cv;
  cv.b = __float2bfloat16(v);
  unsigned int vv = cv.u;
  asm volatile("global_store_short %0, %1, off" :: "v"(p), "v"(vv) : "memory");
}

// Stage ROWSx64 bf16 tile -> LDS [ROWS][64], slot-swizzled (slot s of row r
// holds k-slot s^(r&7)); linear LDS dest + inverse-swizzled global source.
template <int ROWS, int AUX>
__device__ __forceinline__ void stageT(const __hip_bfloat16* __restrict__ src,
                                       int strideElts, int row0, int k0,
                                       unsigned short* lds, int tid) {
  constexpr int CH = ROWS * 8;
#pragma unroll
  for (int it = 0; it * 256 < CH; ++it) {
    int wbase = it * 256 + ((tid >> 6) << 6);
    if (wbase < CH) {
      int chunk = it * 256 + tid;
      int row = chunk >> 3, slot = chunk & 7;
      int ksrc = (slot ^ (row & 7)) << 3;
      const __hip_bfloat16* g = src + (size_t)(row0 + row) * strideElts + (k0 + ksrc);
      unsigned short* l = lds + (size_t)wbase * 8;
      __builtin_amdgcn_global_load_lds(
          (const __attribute__((address_space(1))) unsigned int*)g,
          (__attribute__((address_space(3))) unsigned int*)l, 16, 0, AUX);
    }
  }
}

__device__ __forceinline__ short8 ldfrag(const unsigned short* lds, int row, int slot) {
  int s = slot ^ (row & 7);
  return *(const short8*)(lds + row * 64 + s * 8);
}

// Counted-vmcnt mainloop: A-depth 4 (6 buffers), B-depth 2 (3 buffers).
// B tiles 0,1 prestaged before the strip barrier (its vmcnt(0) drains them).
// kt=0: A0..A3 outstanding -> vmcnt(3) forces A0. kt=1: A1..A4+B2 ->
// vmcnt(3+PB) forces A1. kt>=2: younger-than-B[kt] = A[kt+3]+B[kt+1] ->
// vmcnt(1+PB). Non-issuing waves inherit via s_barrier.
template <int NT, int PB, typename SA, typename SB, typename CC>
__device__ __forceinline__ void gloop(SA sa, SB sb, CC cc) {
  sa(0, 0); sa(1, 1); sa(2, 2); sa(3, 3);
#pragma unroll 1
  for (int kt = 0; kt < NT; ++kt) {
    if (kt == 0)
      asm volatile("s_waitcnt vmcnt(3)" ::: "memory");
    else if (kt == 1)
      asm volatile("s_waitcnt vmcnt(%0)" :: "i"(3 + PB) : "memory");
    else if (kt < NT - 1)
      asm volatile("s_waitcnt vmcnt(%0)" :: "i"(1 + PB) : "memory");
    else
      asm volatile("s_waitcnt vmcnt(0)" ::: "memory");
    __builtin_amdgcn_s_barrier();
    __builtin_amdgcn_sched_barrier(0);
    if (kt + 4 < NT) sa(kt + 4, (kt + 4) % 6);
    if (kt + 2 < NT) sb(kt + 2, (kt + 2) % 3);
    cc(kt % 6, kt % 3);
  }
}

// Strip-local 8-block barrier: monotonic counter, relaxed atomics, no fences.
// All 8 contenders are on one XCD (co-location mapping below); the vmcnt(0)
// drain before arrival makes this wave's plain stores L2-visible first.
__device__ __forceinline__ void sbar(unsigned* scnt, unsigned p) {
  asm volatile("s_waitcnt vmcnt(0)" ::: "memory");  // all waves drain stores
  __syncthreads();
  if (threadIdx.x == 0) {
    __hip_atomic_fetch_add(scnt, 1u, __ATOMIC_RELAXED, __HIP_MEMORY_SCOPE_AGENT);
    while (__hip_atomic_load(scnt, __ATOMIC_RELAXED, __HIP_MEMORY_SCOPE_AGENT) < p * 8u)
      __builtin_amdgcn_s_sleep(1);
  }
  __syncthreads();
  __builtin_amdgcn_sched_barrier(0);
}

__global__ __launch_bounds__(256, 2) void k_fused(
    const float* __restrict__ xg, const float* __restrict__ xtime,
    const __hip_bfloat16* __restrict__ W1t, const float* __restrict__ b1,
    const __hip_bfloat16* __restrict__ W2t, const float* __restrict__ b2,
    const __hip_bfloat16* __restrict__ Wzrt, const float* __restrict__ bz,
    const float* __restrict__ br, const __hip_bfloat16* __restrict__ Wnt,
    const float* __restrict__ bn, float* __restrict__ hf, float* __restrict__ hstdf,
    __hip_bfloat16* __restrict__ hbf, __hip_bfloat16* __restrict__ Ubf,
    __hip_bfloat16* __restrict__ hodeb, __hip_bfloat16* __restrict__ hstdb,
    __hip_bfloat16* __restrict__ A4, __hip_bfloat16* __restrict__ xstep,
    unsigned* __restrict__ bar) {
  __shared__ __align__(16) unsigned short lA[6][16 * 64];    // 12 KB (A depth-4)
  __shared__ __align__(16) unsigned short lB[3][128 * 64];   // 48 KB
  // block-private f32 state for the owned 64 columns (never leaves LDS)
  __shared__ __align__(16) float hloc[16 * 64];              // 4 KB
  __shared__ __align__(16) float hstdloc[16 * 64];           // 4 KB
  __shared__ __align__(16) float hodeloc[16 * 64];           // 4 KB
  __shared__ __align__(16) float zloc[16 * 64];              // 4 KB
  int tid = threadIdx.x, lane = tid & 63, wv = tid >> 6;
  int lr = lane & 15, lg = lane >> 4;
  int b = blockIdx.x;
  // XCD co-location: blockIdx round-robins XCDs (b&7 = XCD, m09). The 64
  // blocks of one XCD form 8 strips x 8 slices so each strip's state exchange
  // stays inside ONE XCD's L2 (plain-store / sc0-load visibility domain).
  // [HARD dependency, declared: if mapping is wrong, absmax explodes.]
  int xcd = b & 7;
  int j = b >> 3;                  // 0..63 within this XCD
  int i = (xcd << 3) | (j >> 3);   // strip 0..63 (8 strips per XCD)
  int s = j & 7;                   // slice 0..7 within strip
  int m0 = i << 4;                 // 16-row strip
  int nA = s << 6;                 // owned 64-column base (all phases)
  unsigned* scnt = bar + i * 32;
  unsigned p = 0;

  // zero private state (h0 = std0 = 0)
  for (int idx = tid; idx < 16 * 64; idx += 256) { hloc[idx] = 0.f; hstdloc[idx] = 0.f; }

  // prestage P1 weight tiles 0,1
  stageT<64, 0>(W1t, H_SZ, nA, 0, lB[0], tid);
  stageT<64, 0>(W1t, H_SZ, nA, 64, lB[1], tid);

#pragma unroll 1
  for (int t = 0; t < T_SZ; ++t) {
    sbar(scnt, ++p);  // strip's hbf/hstdb of step t-1 complete (in local L2)
    // ======== P1: U = tanh(h @ W1 + b1), owned cols ========
    {
      f32x4 acc = {};
      auto sa = [&](int kt, int bi) { stageT<16, AUXS>(hbf, H_SZ, m0, kt << 6, lA[bi], tid); };
      auto sb = [&](int kt, int bi) { stageT<64, 0>(W1t, H_SZ, nA, kt << 6, lB[bi], tid); };
      auto cc = [&](int ai, int bi) {
#pragma unroll
        for (int kk = 0; kk < 2; ++kk) {
          short8 a = ldfrag(lA[ai], lr, (kk << 2) + lg);
          short8 bb = ldfrag(lB[bi], (wv << 4) + lr, (kk << 2) + lg);
          acc = mfma16(a, bb, acc);
        }
      };
      gloop<8, 2>(sa, sb, cc);
      int col = nA + (wv << 4) + lr;
      float bi = b1[col];
#pragma unroll
      for (int r = 0; r < 4; ++r) {
        int rl = (lg << 2) + r;
        st_bf16(&Ubf[(size_t)(m0 + rl) * H_SZ + col], tanhf(acc[r] + bi));
      }
      stageT<64, 0>(W2t, H_SZ, nA, 0, lB[0], tid);   // prestage P2 weights
      stageT<64, 0>(W2t, H_SZ, nA, 64, lB[1], tid);
    }
    sbar(scnt, ++p);
    // ======== P2: h_ode = h + dt*(U @ W2 + b2); x slice -> bf16 ========
    {
      f32x4 acc = {};
      auto sa = [&](int kt, int bi) { stageT<16, AUXS>(Ubf, H_SZ, m0, kt << 6, lA[bi], tid); };
      auto sb = [&](int kt, int bi) { stageT<64, 0>(W2t, H_SZ, nA, kt << 6, lB[bi], tid); };
      auto cc = [&](int ai, int bi) {
#pragma unroll
        for (int kk = 0; kk < 2; ++kk) {
          short8 a = ldfrag(lA[ai], lr, (kk << 2) + lg);
          short8 bb = ldfrag(lB[bi], (wv << 4) + lr, (kk << 2) + lg);
          acc = mfma16(a, bb, acc);
        }
      };
      gloop<8, 2>(sa, sb, cc);
      float dtv = (t == 0) ? 0.01f : (xtime[t] - xtime[t - 1]);
      int cl = (wv << 4) + lr;
      int col = nA + cl;
      float bi = b2[col];
#pragma unroll
      for (int r = 0; r < 4; ++r) {
        int rl = (lg << 2) + r;
        float v = hloc[rl * 64 + cl] + dtv * (acc[r] + bi);
        hodeloc[rl * 64 + cl] = v;
        st_bf16(&hodeb[(size_t)(m0 + rl) * H_SZ + col], v);
      }
      {  // x[:, t, s-slice] -> bf16 (16 strip rows, 32 cols per slice)
        int colx = (s << 5) + (tid & 31);
#pragma unroll
        for (int it2 = 0; it2 < 2; ++it2) {
          int row = m0 + (tid >> 5) + (it2 << 3);
          float xv = xg[((size_t)row * T_SZ + t) * D_SZ + colx];
          st_bf16(&xstep[(size_t)row * D_SZ + colx], xv);
        }
      }
      // prestage P3 weights: [z-rows | r-rows] halves of lB
      stageT<64, 0>(Wzrt, 1280, nA, 0, lB[0], tid);
      stageT<64, 0>(Wzrt, 1280, 512 + nA, 0, lB[0] + 64 * 64, tid);
      stageT<64, 0>(Wzrt, 1280, nA, 64, lB[1], tid);
      stageT<64, 0>(Wzrt, 1280, 512 + nA, 64, lB[1] + 64 * 64, tid);
    }
    sbar(scnt, ++p);
    // ======== P3: z,r = sigmoid(cat @ WzrT) for owned cols; build A4 ========
    {
      f32x4 acc[2] = {};
      auto sa = [&](int kt, int bi) {
        int ke = kt << 6;
        if (ke < 512)       stageT<16, AUXS>(hodeb, H_SZ, m0, ke, lA[bi], tid);
        else if (ke < 1024) stageT<16, AUXS>(hstdb, H_SZ, m0, ke - 512, lA[bi], tid);
        else                stageT<16, AUXS>(xstep, D_SZ, m0, ke - 1024, lA[bi], tid);
      };
      auto sb = [&](int kt, int bi) {
        stageT<64, 0>(Wzrt, 1280, nA, kt << 6, lB[bi], tid);
        stageT<64, 0>(Wzrt, 1280, 512 + nA, kt << 6, lB[bi] + 64 * 64, tid);
      };
      auto cc = [&](int ai, int bi) {
#pragma unroll
        for (int kk = 0; kk < 2; ++kk) {
          short8 a = ldfrag(lA[ai], lr, (kk << 2) + lg);
#pragma unroll
          for (int n = 0; n < 2; ++n) {
            short8 bb = ldfrag(lB[bi], (wv << 5) + (n << 4) + lr, (kk << 2) + lg);
            acc[n] = mfma16(a, bb, acc[n]);
          }
        }
      };
      gloop<20, 4>(sa, sb, cc);
      if (wv < 2) {  // z: local rows 0..63 of lB -> zloc
#pragma unroll
        for (int n = 0; n < 2; ++n) {
          int cl = (wv << 5) + (n << 4) + lr;   // 0..63
          float bi = bz[nA + cl];
#pragma unroll
          for (int r = 0; r < 4; ++r) {
            int rl = (lg << 2) + r;
            zloc[rl * 64 + cl] = 1.f / (1.f + expf(-(acc[n][r] + bi)));
          }
        }
      } else {  // r: local rows 64..127 -> A4 = [h_ode*r | hstd*r]
#pragma unroll
        for (int n = 0; n < 2; ++n) {
          int cl = ((wv - 2) << 5) + (n << 4) + lr;  // 0..63
          int j2 = nA + cl;
          float bi = br[j2];
#pragma unroll
          for (int r = 0; r < 4; ++r) {
            int rl = (lg << 2) + r;
            int row = m0 + rl;
            float g = 1.f / (1.f + expf(-(acc[n][r] + bi)));
            st_bf16(&A4[(size_t)row * 1024 + j2], hodeloc[rl * 64 + cl] * g);
            st_bf16(&A4[(size_t)row * 1024 + 512 + j2], hstdloc[rl * 64 + cl] * g);
          }
        }
      }
      // prestage P4 weights: [mean-rows | std-rows]
      stageT<64, 0>(Wnt, 1280, nA, 0, lB[0], tid);
      stageT<64, 0>(Wnt, 1280, 512 + nA, 0, lB[0] + 64 * 64, tid);
      stageT<64, 0>(Wnt, 1280, nA, 64, lB[1], tid);
      stageT<64, 0>(Wnt, 1280, 512 + nA, 64, lB[1] + 64 * 64, tid);
    }
    sbar(scnt, ++p);
    // ======== P4: n_mean,n_std for owned cols; GRU update in LDS ========
    {
      f32x4 acc[2] = {};
      auto sa = [&](int kt, int bi) {
        int ke = kt << 6;
        if (ke < 1024) stageT<16, AUXS>(A4, 1024, m0, ke, lA[bi], tid);
        else           stageT<16, AUXS>(xstep, D_SZ, m0, ke - 1024, lA[bi], tid);
      };
      auto sb = [&](int kt, int bi) {
        stageT<64, 0>(Wnt, 1280, nA, kt << 6, lB[bi], tid);
        stageT<64, 0>(Wnt, 1280, 512 + nA, kt << 6, lB[bi] + 64 * 64, tid);
      };
      auto cc = [&](int ai, int bi) {
#pragma unroll
        for (int kk = 0; kk < 2; ++kk) {
          short8 a = ldfrag(lA[ai], lr, (kk << 2) + lg);
#pragma unroll
          for (int n = 0; n < 2; ++n) {
            short8 bb = ldfrag(lB[bi], (wv << 5) + (n << 4) + lr, (kk << 2) + lg);
            acc[n] = mfma16(a, bb, acc[n]);
          }
        }
      };
      gloop<20, 4>(sa, sb, cc);
      if (wv < 2) {  // mean cols -> h update (hloc + hbf)
#pragma unroll
        for (int n = 0; n < 2; ++n) {
          int cl = (wv << 5) + (n << 4) + lr;
          int c = nA + cl;
          float bi = bn[c];
#pragma unroll
          for (int r = 0; r < 4; ++r) {
            int rl = (lg << 2) + r;
            float nm = acc[n][r] + bi;
            float z = zloc[rl * 64 + cl], ho = hodeloc[rl * 64 + cl];
            float hn = (1.f - z) * nm + z * ho;
            hloc[rl * 64 + cl] = hn;
            st_bf16(&hbf[(size_t)(m0 + rl) * H_SZ + c], hn);
          }
        }
      } else {  // std cols -> hstd update (hstdloc + hstdb)
#pragma unroll
        for (int n = 0; n < 2; ++n) {
          int cl = ((wv - 2) << 5) + (n << 4) + lr;
          int j2 = nA + cl;
          float bi = bn[512 + j2];
#pragma unroll
          for (int r = 0; r < 4; ++r) {
            int rl = (lg << 2) + r;
            float ns = fabsf(acc[n][r] + bi);
            float z = zloc[rl * 64 + cl], hs = hstdloc[rl * 64 + cl];
            float sn = fabsf((1.f - z) * ns + z * hs);
            hstdloc[rl * 64 + cl] = sn;
            st_bf16(&hstdb[(size_t)(m0 + rl) * H_SZ + j2], sn);
          }
        }
      }
      stageT<64, 0>(W1t, H_SZ, nA, 0, lB[0], tid);   // prestage next-step P1
      stageT<64, 0>(W1t, H_SZ, nA, 64, lB[1], tid);
    }
  }
  // final output: private f32 state -> global (kernel-end flush covers memcpy)
  __syncthreads();
  for (int idx = tid; idx < 16 * 64; idx += 256) {
    int rl = idx >> 6, cl = idx & 63;
    hf[(size_t)(m0 + rl) * H_SZ + nA + cl] = hloc[idx];
    hstdf[(size_t)(m0 + rl) * H_SZ + nA + cl] = hstdloc[idx];
  }
}

// =============== prep: W[k][n] f32  ->  Wt[n][k] bf16 =====================
__global__ void k_wt(const float* __restrict__ W, __hip_bfloat16* __restrict__ Wt,
                     int K, int N, int ld) {
  size_t i = (size_t)blockIdx.x * 256 + threadIdx.x;
  if (i >= (size_t)K * N) return;
  int n = (int)(i / K), k = (int)(i % K);
  Wt[(size_t)n * ld + k] = __float2bfloat16(W[(size_t)k * N + n]);
}

extern "C" void kernel_launch(void* const* d_in, const int* in_sizes, int n_in,
                              void* d_out, int out_size, void* d_ws, size_t ws_size,
                              hipStream_t stream) {
  const float* x     = (const float*)d_in[0];
  const float* xtime = (const float*)d_in[1];
  const float* W1    = (const float*)d_in[2];
  const float* b1    = (const float*)d_in[3];
  const float* W2    = (const float*)d_in[4];
  const float* b2    = (const float*)d_in[5];
  const float* Wz    = (const float*)d_in[6];
  const float* bz    = (const float*)d_in[7];
  const float* Wr    = (const float*)d_in[8];
  const float* br    = (const float*)d_in[9];
  const float* Wn    = (const float*)d_in[10];
  const float* bn    = (const float*)d_in[11];

  char* p = (char*)d_ws;
  __hip_bfloat16* W1t   = (__hip_bfloat16*)(p + 0);
  __hip_bfloat16* W2t   = (__hip_bfloat16*)(p + 524288);
  __hip_bfloat16* Wzrt  = (__hip_bfloat16*)(p + 1048576);
  __hip_bfloat16* Wnt   = (__hip_bfloat16*)(p + 3670016);
  float*          hf    = (float*)(p + 6291456);
  float*          hstdf = (float*)(p + 8388608);
  __hip_bfloat16* hbf   = (__hip_bfloat16*)(p + 14680064);
  __hip_bfloat16* Ubf   = (__hip_bfloat16*)(p + 15728640);
  __hip_bfloat16* hodeb = (__hip_bfloat16*)(p + 16777216);
  __hip_bfloat16* hstdb = (__hip_bfloat16*)(p + 17825792);
  __hip_bfloat16* A4    = (__hip_bfloat16*)(p + 18874368);
  __hip_bfloat16* xstep = (__hip_bfloat16*)(p + 20971520);
  unsigned*       bar   = (unsigned*)(p + 21495808);

  hipMemsetAsync(hbf, 0, 1048576, stream);
  hipMemsetAsync(hstdb, 0, 1048576, stream);
  hipMemsetAsync(bar, 0, 8192, stream);

  k_wt<<<(512 * 512 + 255) / 256, 256, 0, stream>>>(W1, W1t, 512, 512, 512);
  k_wt<<<(512 * 512 + 255) / 256, 256, 0, stream>>>(W2, W2t, 512, 512, 512);
  k_wt<<<(1280 * 512 + 255) / 256, 256, 0, stream>>>(Wz, Wzrt, 1280, 512, 1280);
  k_wt<<<(1280 * 512 + 255) / 256, 256, 0, stream>>>(Wr, Wzrt + (size_t)512 * 1280, 1280, 512, 1280);
  k_wt<<<(1280 * 1024 + 255) / 256, 256, 0, stream>>>(Wn, Wnt, 1280, 1024, 1280);

  // persistent kernel: 64 strips x 8 slices co-located per XCD; state flows
  // through XCD-local L2 (plain write-back stores + sc0 loads)
  k_fused<<<NBLK, 256, 0, stream>>>(x, xtime, W1t, b1, W2t, b2, Wzrt, bz, br,
                                    Wnt, bn, hf, hstdf, hbf, Ubf,
                                    hodeb, hstdb, A4, xstep, bar);

  hipMemcpyAsync(d_out, hf, 2097152, hipMemcpyDeviceToDevice, stream);
  hipMemcpyAsync((char*)d_out + 2097152, hstdf, 2097152, hipMemcpyDeviceToDevice, stream);
}

// Round 12
// 5771.111 us; speedup vs baseline: 1.1914x; 1.1914x over previous
//
#include <hip/hip_runtime.h>
#include <hip/hip_bf16.h>

#define B_SZ 1024
#define T_SZ 128
#define D_SZ 256
#define H_SZ 512
#define NBLK 512
#define AUXS 0x1   // SC0 loads: bypass L1 (stale-line hazard), hit L2/L3

typedef __attribute__((ext_vector_type(8))) short short8;
typedef __attribute__((ext_vector_type(4))) float f32x4;

__device__ inline f32x4 mfma16(short8 a, short8 b, f32x4 c) {
  return __builtin_amdgcn_mfma_f32_16x16x32_bf16(a, b, c, 0, 0, 0);
}

__device__ inline void st_bf16(__hip_bfloat16* p, float v) {
  union { __hip_bfloat16 b; unsigned short u; } cv;
  cv.b = __float2bfloat16(v);
  unsigned int vv = cv.u;
  asm volatile("global_store_short %0, %1, off" :: "v"(p), "v"(vv) : "memory");
}

// Stage ROWSx64 bf16 tile -> LDS [ROWS][64], slot-swizzled (slot s of row r
// holds k-slot s^(r&7)); linear LDS dest + inverse-swizzled global source.
// stageT<16>: 1 instr on waves 0-1 only. stageT<64>: 2 instrs on every wave.
template <int ROWS, int AUX>
__device__ __forceinline__ void stageT(const __hip_bfloat16* __restrict__ src,
                                       int strideElts, int row0, int k0,
                                       unsigned short* lds, int tid) {
  constexpr int CH = ROWS * 8;
#pragma unroll
  for (int it = 0; it * 256 < CH; ++it) {
    int wbase = it * 256 + ((tid >> 6) << 6);
    if (wbase < CH) {
      int chunk = it * 256 + tid;
      int row = chunk >> 3, slot = chunk & 7;
      int ksrc = (slot ^ (row & 7)) << 3;
      const __hip_bfloat16* g = src + (size_t)(row0 + row) * strideElts + (k0 + ksrc);
      unsigned short* l = lds + (size_t)wbase * 8;
      __builtin_amdgcn_global_load_lds(
          (const __attribute__((address_space(1))) unsigned int*)g,
          (__attribute__((address_space(3))) unsigned int*)l, 16, 0, AUX);
    }
  }
}

__device__ __forceinline__ short8 ldfrag(const unsigned short* lds, int row, int slot) {
  int s = slot ^ (row & 7);
  return *(const short8*)(lds + row * 64 + s * 8);
}

// Counted-vmcnt mainloop, B-BEFORE-A issue order. B depth-3 (4 buffers,
// B[0..2] prestaged & drained by the preceding sbar), A depth-4 (5 buffers,
// A[0..3] issued at entry). Per-wave in-order vmcnt derivation:
//  waves 0-1 (issue 1 A instr + PB B instrs/iter; per-iter order B[kt+3],A[kt+4]):
//   kt=0: outstanding A0..A3 -> need A0 -> vmcnt(3)
//   kt=1: A1..A3,B3,A4 -> need A1 -> vmcnt(3+PB)
//   2<=kt<=NT-4: ...A[kt],B[kt],A[kt+1],B[kt+1],A[kt+2],B[kt+2],A[kt+3] ->
//     force B[kt] (also forces older A[kt]) -> vmcnt(3+2PB)
//   kt=NT-3: vmcnt(2+2PB); kt=NT-2: vmcnt(1+PB); kt=NT-1: vmcnt(0)
//  waves 2-3 (B only): kt<=NT-3: vmcnt(2PB); NT-2: vmcnt(PB); NT-1: 0.
// Every wave forces ITS OWN chunks of A[kt],B[kt] before the barrier, so all
// cross-wave LDS reads after the barrier are safe. Buffer-reuse safety: the
// compiler's lgkmcnt before each MFMA retires reads one full iter before the
// overwrite of that buffer.
template <int NT, int PB, typename SA, typename SB, typename CC>
__device__ __forceinline__ void gloop(int wv, SA sa, SB sb, CC cc) {
  sa(0, 0); sa(1, 1); sa(2, 2); sa(3, 3);
#pragma unroll 1
  for (int kt = 0; kt < NT; ++kt) {
    if (wv < 2) {
      if (kt == 0)           asm volatile("s_waitcnt vmcnt(3)" ::: "memory");
      else if (kt == 1)      asm volatile("s_waitcnt vmcnt(%0)" :: "i"(3 + PB) : "memory");
      else if (kt <= NT - 4) asm volatile("s_waitcnt vmcnt(%0)" :: "i"(3 + 2 * PB) : "memory");
      else if (kt == NT - 3) asm volatile("s_waitcnt vmcnt(%0)" :: "i"(2 + 2 * PB) : "memory");
      else if (kt == NT - 2) asm volatile("s_waitcnt vmcnt(%0)" :: "i"(1 + PB) : "memory");
      else                   asm volatile("s_waitcnt vmcnt(0)" ::: "memory");
    } else {
      if (kt <= NT - 3)      asm volatile("s_waitcnt vmcnt(%0)" :: "i"(2 * PB) : "memory");
      else if (kt == NT - 2) asm volatile("s_waitcnt vmcnt(%0)" :: "i"(PB) : "memory");
      else                   asm volatile("s_waitcnt vmcnt(0)" ::: "memory");
    }
    __builtin_amdgcn_s_barrier();
    __builtin_amdgcn_sched_barrier(0);
    if (kt + 3 < NT) sb(kt + 3, (kt + 3) & 3);
    if (kt + 4 < NT) sa(kt + 4, (kt + 4) % 5);
    cc(kt % 5, kt & 3);
  }
}

// Strip-local 8-block barrier: monotonic counter, relaxed atomics, no fences.
__device__ __forceinline__ void sbar(unsigned* scnt, unsigned p) {
  asm volatile("s_waitcnt vmcnt(0)" ::: "memory");  // all waves drain stores
  __syncthreads();
  if (threadIdx.x == 0) {
    __hip_atomic_fetch_add(scnt, 1u, __ATOMIC_RELAXED, __HIP_MEMORY_SCOPE_AGENT);
    while (__hip_atomic_load(scnt, __ATOMIC_RELAXED, __HIP_MEMORY_SCOPE_AGENT) < p * 8u)
      __builtin_amdgcn_s_sleep(1);
  }
  __syncthreads();
  __builtin_amdgcn_sched_barrier(0);
}

__global__ __launch_bounds__(256, 2) void k_fused(
    const float* __restrict__ xg, const float* __restrict__ xtime,
    const __hip_bfloat16* __restrict__ W1t, const float* __restrict__ b1,
    const __hip_bfloat16* __restrict__ W2t, const float* __restrict__ b2,
    const __hip_bfloat16* __restrict__ Wzrt, const float* __restrict__ bz,
    const float* __restrict__ br, const __hip_bfloat16* __restrict__ Wnt,
    const float* __restrict__ bn, float* __restrict__ hf, float* __restrict__ hstdf,
    __hip_bfloat16* __restrict__ hbf, __hip_bfloat16* __restrict__ Ubf,
    __hip_bfloat16* __restrict__ hodeb, __hip_bfloat16* __restrict__ hstdb,
    __hip_bfloat16* __restrict__ A4, __hip_bfloat16* __restrict__ xstep,
    unsigned* __restrict__ bar) {
  __shared__ __align__(16) unsigned short lA[5][16 * 64];    // 10 KB, A depth-4
  __shared__ __align__(16) unsigned short lB[4][128 * 64];   // 64 KB, B depth-3
  int tid = threadIdx.x, lane = tid & 63, wv = tid >> 6;
  int lr = lane & 15, lg = lane >> 4;
  int b = blockIdx.x;
  // strip co-location per XCD (b&7 = XCD round-robin); perf heuristic only,
  // visibility is via memory + vmcnt drain as proven in r9-r11.
  int xcd = b & 7;
  int j = b >> 3;
  int i = (xcd << 3) | (j >> 3);   // strip 0..63
  int s = j & 7;                   // slice 0..7
  int m0 = i << 4;                 // 16-row strip
  int nA = s << 6;                 // owned 64-column base (ALL phases)
  unsigned* scnt = bar + i * 32;
  unsigned p = 0;
  // per-thread owned cell: rows m0+(lg*4+r), col nA+(wv*16+lr). ALL f32 state
  // (h, hstd, h_ode, z) lives in these 16 registers, never in LDS/global.
  int cl = (wv << 4) + lr;
  int col = nA + cl;
  float hreg[4] = {0.f, 0.f, 0.f, 0.f}, sreg[4] = {0.f, 0.f, 0.f, 0.f};
  float oreg[4], zreg[4];

  // prestage P1 weight tiles 0..2 (drained by the first sbar)
  stageT<64, 0>(W1t, H_SZ, nA, 0, lB[0], tid);
  stageT<64, 0>(W1t, H_SZ, nA, 64, lB[1], tid);
  stageT<64, 0>(W1t, H_SZ, nA, 128, lB[2], tid);

#pragma unroll 1
  for (int t = 0; t < T_SZ; ++t) {
    sbar(scnt, ++p);  // strip's hbf/hstdb of step t-1 visible
    // ======== P1: U = tanh(h @ W1 + b1), owned cols ========
    {
      f32x4 acc = {};
      auto sa = [&](int kt, int bi) { stageT<16, AUXS>(hbf, H_SZ, m0, kt << 6, lA[bi], tid); };
      auto sb = [&](int kt, int bi) { stageT<64, 0>(W1t, H_SZ, nA, kt << 6, lB[bi], tid); };
      auto cc = [&](int ai, int bi) {
#pragma unroll
        for (int kk = 0; kk < 2; ++kk) {
          short8 a = ldfrag(lA[ai], lr, (kk << 2) + lg);
          short8 bb = ldfrag(lB[bi], cl, (kk << 2) + lg);
          acc = mfma16(a, bb, acc);
        }
      };
      gloop<8, 2>(wv, sa, sb, cc);
      float bi = b1[col];
#pragma unroll
      for (int r = 0; r < 4; ++r)
        st_bf16(&Ubf[(size_t)(m0 + (lg << 2) + r) * H_SZ + col], tanhf(acc[r] + bi));
      stageT<64, 0>(W2t, H_SZ, nA, 0, lB[0], tid);   // prestage P2 B0..2
      stageT<64, 0>(W2t, H_SZ, nA, 64, lB[1], tid);
      stageT<64, 0>(W2t, H_SZ, nA, 128, lB[2], tid);
    }
    sbar(scnt, ++p);
    // ======== P2: h_ode = h + dt*(U @ W2 + b2); x slice -> bf16 ========
    {
      f32x4 acc = {};
      auto sa = [&](int kt, int bi) { stageT<16, AUXS>(Ubf, H_SZ, m0, kt << 6, lA[bi], tid); };
      auto sb = [&](int kt, int bi) { stageT<64, 0>(W2t, H_SZ, nA, kt << 6, lB[bi], tid); };
      auto cc = [&](int ai, int bi) {
#pragma unroll
        for (int kk = 0; kk < 2; ++kk) {
          short8 a = ldfrag(lA[ai], lr, (kk << 2) + lg);
          short8 bb = ldfrag(lB[bi], cl, (kk << 2) + lg);
          acc = mfma16(a, bb, acc);
        }
      };
      gloop<8, 2>(wv, sa, sb, cc);
      float dtv = (t == 0) ? 0.01f : (xtime[t] - xtime[t - 1]);
      float bi = b2[col];
#pragma unroll
      for (int r = 0; r < 4; ++r) {
        float v = hreg[r] + dtv * (acc[r] + bi);
        oreg[r] = v;
        st_bf16(&hodeb[(size_t)(m0 + (lg << 2) + r) * H_SZ + col], v);
      }
      {  // x[:, t, s-slice] -> bf16 (16 strip rows, 32 cols per slice)
        int colx = (s << 5) + (tid & 31);
#pragma unroll
        for (int it2 = 0; it2 < 2; ++it2) {
          int row = m0 + (tid >> 5) + (it2 << 3);
          float xv = xg[((size_t)row * T_SZ + t) * D_SZ + colx];
          st_bf16(&xstep[(size_t)row * D_SZ + colx], xv);
        }
      }
#pragma unroll
      for (int q = 0; q < 3; ++q) {  // prestage P3 B0..2 ([z-half | r-half])
        stageT<64, 0>(Wzrt, 1280, nA, q << 6, lB[q], tid);
        stageT<64, 0>(Wzrt, 1280, 512 + nA, q << 6, lB[q] + 64 * 64, tid);
      }
    }
    sbar(scnt, ++p);
    // ======== P3: z,r = sigmoid(cat @ WzrT), owned cols; build A4 ========
    {
      f32x4 acc0 = {}, acc1 = {};
      auto sa = [&](int kt, int bi) {
        int ke = kt << 6;
        if (ke < 512)       stageT<16, AUXS>(hodeb, H_SZ, m0, ke, lA[bi], tid);
        else if (ke < 1024) stageT<16, AUXS>(hstdb, H_SZ, m0, ke - 512, lA[bi], tid);
        else                stageT<16, AUXS>(xstep, D_SZ, m0, ke - 1024, lA[bi], tid);
      };
      auto sb = [&](int kt, int bi) {
        stageT<64, 0>(Wzrt, 1280, nA, kt << 6, lB[bi], tid);
        stageT<64, 0>(Wzrt, 1280, 512 + nA, kt << 6, lB[bi] + 64 * 64, tid);
      };
      auto cc = [&](int ai, int bi) {
#pragma unroll
        for (int kk = 0; kk < 2; ++kk) {
          short8 a = ldfrag(lA[ai], lr, (kk << 2) + lg);
          short8 b0 = ldfrag(lB[bi], cl, (kk << 2) + lg);          // z-cols
          short8 b1f = ldfrag(lB[bi], 64 + cl, (kk << 2) + lg);    // r-cols
          acc0 = mfma16(a, b0, acc0);
          acc1 = mfma16(a, b1f, acc1);
        }
      };
      gloop<20, 4>(wv, sa, sb, cc);
      float bz_ = bz[col], br_ = br[col];
#pragma unroll
      for (int r = 0; r < 4; ++r) {
        int row = m0 + (lg << 2) + r;
        zreg[r] = 1.f / (1.f + expf(-(acc0[r] + bz_)));
        float g = 1.f / (1.f + expf(-(acc1[r] + br_)));
        st_bf16(&A4[(size_t)row * 1024 + col], oreg[r] * g);
        st_bf16(&A4[(size_t)row * 1024 + 512 + col], sreg[r] * g);
      }
#pragma unroll
      for (int q = 0; q < 3; ++q) {  // prestage P4 B0..2 ([mean | std])
        stageT<64, 0>(Wnt, 1280, nA, q << 6, lB[q], tid);
        stageT<64, 0>(Wnt, 1280, 512 + nA, q << 6, lB[q] + 64 * 64, tid);
      }
    }
    sbar(scnt, ++p);
    // ======== P4: n_mean,n_std owned cols; GRU update in registers ========
    {
      f32x4 acc0 = {}, acc1 = {};
      auto sa = [&](int kt, int bi) {
        int ke = kt << 6;
        if (ke < 1024) stageT<16, AUXS>(A4, 1024, m0, ke, lA[bi], tid);
        else           stageT<16, AUXS>(xstep, D_SZ, m0, ke - 1024, lA[bi], tid);
      };
      auto sb = [&](int kt, int bi) {
        stageT<64, 0>(Wnt, 1280, nA, kt << 6, lB[bi], tid);
        stageT<64, 0>(Wnt, 1280, 512 + nA, kt << 6, lB[bi] + 64 * 64, tid);
      };
      auto cc = [&](int ai, int bi) {
#pragma unroll
        for (int kk = 0; kk < 2; ++kk) {
          short8 a = ldfrag(lA[ai], lr, (kk << 2) + lg);
          short8 b0 = ldfrag(lB[bi], cl, (kk << 2) + lg);          // mean
          short8 b1f = ldfrag(lB[bi], 64 + cl, (kk << 2) + lg);    // std
          acc0 = mfma16(a, b0, acc0);
          acc1 = mfma16(a, b1f, acc1);
        }
      };
      gloop<20, 4>(wv, sa, sb, cc);
      float bm = bn[col], bs = bn[512 + col];
#pragma unroll
      for (int r = 0; r < 4; ++r) {
        int row = m0 + (lg << 2) + r;
        float z = zreg[r];
        float hn = (1.f - z) * (acc0[r] + bm) + z * oreg[r];
        hreg[r] = hn;
        st_bf16(&hbf[(size_t)row * H_SZ + col], hn);
        float ns = fabsf(acc1[r] + bs);
        float sn = fabsf((1.f - z) * ns + z * sreg[r]);
        sreg[r] = sn;
        st_bf16(&hstdb[(size_t)row * H_SZ + col], sn);
      }
      stageT<64, 0>(W1t, H_SZ, nA, 0, lB[0], tid);   // prestage next P1 B0..2
      stageT<64, 0>(W1t, H_SZ, nA, 64, lB[1], tid);
      stageT<64, 0>(W1t, H_SZ, nA, 128, lB[2], tid);
    }
  }
  // final output: register state -> global (kernel-end flush covers memcpy)
#pragma unroll
  for (int r = 0; r < 4; ++r) {
    int row = m0 + (lg << 2) + r;
    hf[(size_t)row * H_SZ + col] = hreg[r];
    hstdf[(size_t)row * H_SZ + col] = sreg[r];
  }
}

// =============== prep: W[k][n] f32  ->  Wt[n][k] bf16 =====================
__global__ void k_wt(const float* __restrict__ W, __hip_bfloat16* __restrict__ Wt,
                     int K, int N, int ld) {
  size_t i = (size_t)blockIdx.x * 256 + threadIdx.x;
  if (i >= (size_t)K * N) return;
  int n = (int)(i / K), k = (int)(i % K);
  Wt[(size_t)n * ld + k] = __float2bfloat16(W[(size_t)k * N + n]);
}

extern "C" void kernel_launch(void* const* d_in, const int* in_sizes, int n_in,
                              void* d_out, int out_size, void* d_ws, size_t ws_size,
                              hipStream_t stream) {
  const float* x     = (const float*)d_in[0];
  const float* xtime = (const float*)d_in[1];
  const float* W1    = (const float*)d_in[2];
  const float* b1    = (const float*)d_in[3];
  const float* W2    = (const float*)d_in[4];
  const float* b2    = (const float*)d_in[5];
  const float* Wz    = (const float*)d_in[6];
  const float* bz    = (const float*)d_in[7];
  const float* Wr    = (const float*)d_in[8];
  const float* br    = (const float*)d_in[9];
  const float* Wn    = (const float*)d_in[10];
  const float* bn    = (const float*)d_in[11];

  char* p = (char*)d_ws;
  __hip_bfloat16* W1t   = (__hip_bfloat16*)(p + 0);
  __hip_bfloat16* W2t   = (__hip_bfloat16*)(p + 524288);
  __hip_bfloat16* Wzrt  = (__hip_bfloat16*)(p + 1048576);
  __hip_bfloat16* Wnt   = (__hip_bfloat16*)(p + 3670016);
  float*          hf    = (float*)(p + 6291456);
  float*          hstdf = (float*)(p + 8388608);
  __hip_bfloat16* hbf   = (__hip_bfloat16*)(p + 14680064);
  __hip_bfloat16* Ubf   = (__hip_bfloat16*)(p + 15728640);
  __hip_bfloat16* hodeb = (__hip_bfloat16*)(p + 16777216);
  __hip_bfloat16* hstdb = (__hip_bfloat16*)(p + 17825792);
  __hip_bfloat16* A4    = (__hip_bfloat16*)(p + 18874368);
  __hip_bfloat16* xstep = (__hip_bfloat16*)(p + 20971520);
  unsigned*       bar   = (unsigned*)(p + 21495808);

  hipMemsetAsync(hbf, 0, 1048576, stream);
  hipMemsetAsync(hstdb, 0, 1048576, stream);
  hipMemsetAsync(bar, 0, 8192, stream);

  k_wt<<<(512 * 512 + 255) / 256, 256, 0, stream>>>(W1, W1t, 512, 512, 512);
  k_wt<<<(512 * 512 + 255) / 256, 256, 0, stream>>>(W2, W2t, 512, 512, 512);
  k_wt<<<(1280 * 512 + 255) / 256, 256, 0, stream>>>(Wz, Wzrt, 1280, 512, 1280);
  k_wt<<<(1280 * 512 + 255) / 256, 256, 0, stream>>>(Wr, Wzrt + (size_t)512 * 1280, 1280, 512, 1280);
  k_wt<<<(1280 * 1024 + 255) / 256, 256, 0, stream>>>(Wn, Wnt, 1280, 1024, 1280);

  // persistent kernel: 64 strips x 8 slices; f32 state in registers; B-first
  // counted-vmcnt pipeline (A 4-deep, B 3-deep); strip-local 8-block barriers
  k_fused<<<NBLK, 256, 0, stream>>>(x, xtime, W1t, b1, W2t, b2, Wzrt, bz, br,
                                    Wnt, bn, hf, hstdf, hbf, Ubf,
                                    hodeb, hstdb, A4, xstep, bar);

  hipMemcpyAsync(d_out, hf, 2097152, hipMemcpyDeviceToDevice, stream);
  hipMemcpyAsync((char*)d_out + 2097152, hstdf, 2097152, hipMemcpyDeviceToDevice, stream);
}

// Round 13
// 4995.861 us; speedup vs baseline: 1.3763x; 1.1552x over previous
//
#include <hip/hip_runtime.h>
#include <hip/hip_bf16.h>

#define B_SZ 1024
#define T_SZ 128
#define D_SZ 256
#define H_SZ 512
#define NBLK 256
#define NTHR 512
#define AUXS 0x1   // SC0 loads: bypass L1 (stale-line hazard), hit L2/L3

typedef __attribute__((ext_vector_type(8))) short short8;
typedef __attribute__((ext_vector_type(4))) float f32x4;

__device__ inline f32x4 mfma16(short8 a, short8 b, f32x4 c) {
  return __builtin_amdgcn_mfma_f32_16x16x32_bf16(a, b, c, 0, 0, 0);
}

__device__ inline void st_bf16(__hip_bfloat16* p, float v) {
  union { __hip_bfloat16 b; unsigned short u; } cv;
  cv.b = __float2bfloat16(v);
  unsigned int vv = cv.u;
  asm volatile("global_store_short %0, %1, off" :: "v"(p), "v"(vv) : "memory");
}

// Stage ROWSx64 bf16 tile -> LDS [ROWS][64], slot-swizzled (slot s of row r
// holds k-slot s^(r&7)); linear LDS dest + inverse-swizzled global source.
// 512-thread block: ROWS=32 -> waves 0-3 issue 1 instr (waves 4-7 none);
// ROWS=64 -> every wave 1 instr.
template <int ROWS, int AUX>
__device__ __forceinline__ void stage512(const __hip_bfloat16* __restrict__ src,
                                         int strideElts, int row0, int k0,
                                         unsigned short* lds, int tid) {
  constexpr int CH = ROWS * 8;
#pragma unroll
  for (int it = 0; it * NTHR < CH; ++it) {
    int wbase = it * NTHR + ((tid >> 6) << 6);
    if (wbase < CH) {
      int chunk = it * NTHR + tid;
      int row = chunk >> 3, slot = chunk & 7;
      int ksrc = (slot ^ (row & 7)) << 3;
      const __hip_bfloat16* g = src + (size_t)(row0 + row) * strideElts + (k0 + ksrc);
      unsigned short* l = lds + (size_t)wbase * 8;
      __builtin_amdgcn_global_load_lds(
          (const __attribute__((address_space(1))) unsigned int*)g,
          (__attribute__((address_space(3))) unsigned int*)l, 16, 0, AUX);
    }
  }
}

__device__ __forceinline__ short8 ldfrag(const unsigned short* lds, int row, int slot) {
  int s = slot ^ (row & 7);
  return *(const short8*)(lds + row * 64 + s * 8);
}

// Counted-vmcnt mainloop, 8 waves. A depth-4 (5 buffers, waves 0-3 issue, 1
// instr each), B depth-3 (4 buffers, B0..2 prestaged pre-gloop, PB instrs per
// wave per tile). Per-iter order: wait, barrier, sb(kt+3), sa(kt+4), cc(kt).
// In-order vmcnt per wave class:
//  waves 0-3 (1 A instr + PB B instrs/iter; full order B0..2,A0..3,
//  [B3,A4],[B4,A5],...):
//   kt=0: force A0 -> vmcnt(3)            kt=1: force A1 -> vmcnt(3+PB)
//   2..NT-4: force B[kt] -> vmcnt(3+2PB)  NT-3: vmcnt(2+2PB)
//   NT-2: vmcnt(1+PB)                     NT-1: vmcnt(0)
//  waves 4-7 (B only): <=NT-3: vmcnt(2PB); NT-2: vmcnt(PB); NT-1: 0.
template <int NT, int PB, typename SA, typename SB, typename CC>
__device__ __forceinline__ void gloop(int wv, SA sa, SB sb, CC cc) {
  sa(0, 0); sa(1, 1); sa(2, 2); sa(3, 3);   // waves 4-7 no-op internally
#pragma unroll 1
  for (int kt = 0; kt < NT; ++kt) {
    if (wv < 4) {
      if (kt == 0)           asm volatile("s_waitcnt vmcnt(3)" ::: "memory");
      else if (kt == 1)      asm volatile("s_waitcnt vmcnt(%0)" :: "i"(3 + PB) : "memory");
      else if (kt <= NT - 4) asm volatile("s_waitcnt vmcnt(%0)" :: "i"(3 + 2 * PB) : "memory");
      else if (kt == NT - 3) asm volatile("s_waitcnt vmcnt(%0)" :: "i"(2 + 2 * PB) : "memory");
      else if (kt == NT - 2) asm volatile("s_waitcnt vmcnt(%0)" :: "i"(1 + PB) : "memory");
      else                   asm volatile("s_waitcnt vmcnt(0)" ::: "memory");
    } else {
      if (kt <= NT - 3)      asm volatile("s_waitcnt vmcnt(%0)" :: "i"(2 * PB) : "memory");
      else if (kt == NT - 2) asm volatile("s_waitcnt vmcnt(%0)" :: "i"(PB) : "memory");
      else                   asm volatile("s_waitcnt vmcnt(0)" ::: "memory");
    }
    __builtin_amdgcn_s_barrier();
    __builtin_amdgcn_sched_barrier(0);
    if (kt + 3 < NT) sb(kt + 3, (kt + 3) & 3);
    if (kt + 4 < NT) sa(kt + 4, (kt + 4) % 5);
    cc(kt % 5, kt & 3);
  }
}

// Strip barrier split: arrive (drain stores only) -> [prestage next-phase B
// weights: they fly during the poll] -> wait. Monotonic counter, relaxed
// atomics, no cache-maintenance (r5-r12 proven visibility model).
__device__ __forceinline__ void sbar_arrive(unsigned* scnt) {
  asm volatile("s_waitcnt vmcnt(0)" ::: "memory");  // all waves drain stores
  __syncthreads();
  if (threadIdx.x == 0)
    __hip_atomic_fetch_add(scnt, 1u, __ATOMIC_RELAXED, __HIP_MEMORY_SCOPE_AGENT);
}
__device__ __forceinline__ void sbar_wait(unsigned* scnt, unsigned p) {
  if (threadIdx.x == 0) {
    while (__hip_atomic_load(scnt, __ATOMIC_RELAXED, __HIP_MEMORY_SCOPE_AGENT) < p * 8u)
      __builtin_amdgcn_s_sleep(1);
  }
  __syncthreads();
  __builtin_amdgcn_sched_barrier(0);
}

__global__ __launch_bounds__(512, 2) void k_fused(
    const float* __restrict__ xg, const float* __restrict__ xtime,
    const __hip_bfloat16* __restrict__ W1t, const float* __restrict__ b1,
    const __hip_bfloat16* __restrict__ W2t, const float* __restrict__ b2,
    const __hip_bfloat16* __restrict__ Wzrt, const float* __restrict__ bz,
    const float* __restrict__ br, const __hip_bfloat16* __restrict__ Wnt,
    const float* __restrict__ bn, float* __restrict__ hf, float* __restrict__ hstdf,
    __hip_bfloat16* __restrict__ hbf, __hip_bfloat16* __restrict__ Ubf,
    __hip_bfloat16* __restrict__ hodeb, __hip_bfloat16* __restrict__ hstdb,
    __hip_bfloat16* __restrict__ A4, __hip_bfloat16* __restrict__ xstep,
    unsigned* __restrict__ bar) {
  __shared__ __align__(16) unsigned short lA[5][32 * 64];    // 20 KB, A depth-4
  __shared__ __align__(16) unsigned short lB[4][128 * 64];   // 64 KB, B depth-3
  int tid = threadIdx.x, lane = tid & 63, wv = tid >> 6;
  int lr = lane & 15, lg = lane >> 4;
  int rh = wv >> 2, cq = wv & 3;   // wave role: row-half (0/1), col-quarter
  int b = blockIdx.x;
  int xcd = b & 7;                 // XCD round-robin (perf heuristic only)
  int j = b >> 3;                  // 0..31 within XCD
  int i = (xcd << 2) | (j >> 3);   // strip 0..31 (4 strips per XCD)
  int s = j & 7;                   // slice 0..7
  int m0 = i << 5;                 // 32-row strip
  int nA = s << 6;                 // owned 64-column base (ALL phases)
  unsigned* scnt = bar + i * 32;
  unsigned p = 0;
  // per-thread owned cell: rows m0+(rh*16)+(lg*4+r), col nA+(cq*16)+lr.
  // ALL f32 state (h, hstd, h_ode, z) lives in these registers.
  int cl = (cq << 4) + lr;
  int col = nA + cl;
  int row0 = m0 + (rh << 4) + (lg << 2);
  float hreg[4] = {0.f, 0.f, 0.f, 0.f}, sreg[4] = {0.f, 0.f, 0.f, 0.f};
  float oreg[4], zreg[4];

  // prestage P1 weight tiles 0..2
  stage512<64, 0>(W1t, H_SZ, nA, 0, lB[0], tid);
  stage512<64, 0>(W1t, H_SZ, nA, 64, lB[1], tid);
  stage512<64, 0>(W1t, H_SZ, nA, 128, lB[2], tid);

#pragma unroll 1
  for (int t = 0; t < T_SZ; ++t) {
    // ======== P1: U = tanh(h @ W1 + b1), owned cols ========
    {
      f32x4 acc = {};
      auto sa = [&](int kt, int bi) { stage512<32, AUXS>(hbf, H_SZ, m0, kt << 6, lA[bi], tid); };
      auto sb = [&](int kt, int bi) { stage512<64, 0>(W1t, H_SZ, nA, kt << 6, lB[bi], tid); };
      auto cc = [&](int ai, int bi) {
#pragma unroll
        for (int kk = 0; kk < 2; ++kk) {
          short8 a = ldfrag(lA[ai], (rh << 4) + lr, (kk << 2) + lg);
          short8 bb = ldfrag(lB[bi], cl, (kk << 2) + lg);
          acc = mfma16(a, bb, acc);
        }
      };
      gloop<8, 1>(wv, sa, sb, cc);
      float bi = b1[col];
#pragma unroll
      for (int r = 0; r < 4; ++r)
        st_bf16(&Ubf[(size_t)(row0 + r) * H_SZ + col], tanhf(acc[r] + bi));
    }
    sbar_arrive(scnt);
    stage512<64, 0>(W2t, H_SZ, nA, 0, lB[0], tid);
    stage512<64, 0>(W2t, H_SZ, nA, 64, lB[1], tid);
    stage512<64, 0>(W2t, H_SZ, nA, 128, lB[2], tid);
    sbar_wait(scnt, ++p);
    // ======== P2: h_ode = h + dt*(U @ W2 + b2); x slice -> bf16 ========
    {
      f32x4 acc = {};
      auto sa = [&](int kt, int bi) { stage512<32, AUXS>(Ubf, H_SZ, m0, kt << 6, lA[bi], tid); };
      auto sb = [&](int kt, int bi) { stage512<64, 0>(W2t, H_SZ, nA, kt << 6, lB[bi], tid); };
      auto cc = [&](int ai, int bi) {
#pragma unroll
        for (int kk = 0; kk < 2; ++kk) {
          short8 a = ldfrag(lA[ai], (rh << 4) + lr, (kk << 2) + lg);
          short8 bb = ldfrag(lB[bi], cl, (kk << 2) + lg);
          acc = mfma16(a, bb, acc);
        }
      };
      gloop<8, 1>(wv, sa, sb, cc);
      float dtv = (t == 0) ? 0.01f : (xtime[t] - xtime[t - 1]);
      float bi = b2[col];
#pragma unroll
      for (int r = 0; r < 4; ++r) {
        float v = hreg[r] + dtv * (acc[r] + bi);
        oreg[r] = v;
        st_bf16(&hodeb[(size_t)(row0 + r) * H_SZ + col], v);
      }
      {  // x[:, t, s-slice] -> bf16 (32 strip rows, 32 cols per slice)
        int colx = (s << 5) + (tid & 31);
#pragma unroll
        for (int it2 = 0; it2 < 2; ++it2) {
          int row = m0 + (tid >> 5) + (it2 << 4);
          float xv = xg[((size_t)row * T_SZ + t) * D_SZ + colx];
          st_bf16(&xstep[(size_t)row * D_SZ + colx], xv);
        }
      }
    }
    sbar_arrive(scnt);
#pragma unroll
    for (int q = 0; q < 3; ++q) {  // prestage P3 B0..2 ([z-half | r-half])
      stage512<64, 0>(Wzrt, 1280, nA, q << 6, lB[q], tid);
      stage512<64, 0>(Wzrt, 1280, 512 + nA, q << 6, lB[q] + 64 * 64, tid);
    }
    sbar_wait(scnt, ++p);
    // ======== P3: z,r = sigmoid(cat @ WzrT), owned cols; build A4 ========
    {
      f32x4 acc0 = {}, acc1 = {};
      auto sa = [&](int kt, int bi) {
        int ke = kt << 6;
        if (ke < 512)       stage512<32, AUXS>(hodeb, H_SZ, m0, ke, lA[bi], tid);
        else if (ke < 1024) stage512<32, AUXS>(hstdb, H_SZ, m0, ke - 512, lA[bi], tid);
        else                stage512<32, AUXS>(xstep, D_SZ, m0, ke - 1024, lA[bi], tid);
      };
      auto sb = [&](int kt, int bi) {
        stage512<64, 0>(Wzrt, 1280, nA, kt << 6, lB[bi], tid);
        stage512<64, 0>(Wzrt, 1280, 512 + nA, kt << 6, lB[bi] + 64 * 64, tid);
      };
      auto cc = [&](int ai, int bi) {
#pragma unroll
        for (int kk = 0; kk < 2; ++kk) {
          short8 a = ldfrag(lA[ai], (rh << 4) + lr, (kk << 2) + lg);
          short8 b0 = ldfrag(lB[bi], cl, (kk << 2) + lg);          // z-cols
          short8 b1f = ldfrag(lB[bi], 64 + cl, (kk << 2) + lg);    // r-cols
          acc0 = mfma16(a, b0, acc0);
          acc1 = mfma16(a, b1f, acc1);
        }
      };
      gloop<20, 2>(wv, sa, sb, cc);
      float bz_ = bz[col], br_ = br[col];
#pragma unroll
      for (int r = 0; r < 4; ++r) {
        int row = row0 + r;
        zreg[r] = 1.f / (1.f + expf(-(acc0[r] + bz_)));
        float g = 1.f / (1.f + expf(-(acc1[r] + br_)));
        st_bf16(&A4[(size_t)row * 1024 + col], oreg[r] * g);
        st_bf16(&A4[(size_t)row * 1024 + 512 + col], sreg[r] * g);
      }
    }
    sbar_arrive(scnt);
#pragma unroll
    for (int q = 0; q < 3; ++q) {  // prestage P4 B0..2 ([mean | std])
      stage512<64, 0>(Wnt, 1280, nA, q << 6, lB[q], tid);
      stage512<64, 0>(Wnt, 1280, 512 + nA, q << 6, lB[q] + 64 * 64, tid);
    }
    sbar_wait(scnt, ++p);
    // ======== P4: n_mean,n_std owned cols; GRU update in registers ========
    {
      f32x4 acc0 = {}, acc1 = {};
      auto sa = [&](int kt, int bi) {
        int ke = kt << 6;
        if (ke < 1024) stage512<32, AUXS>(A4, 1024, m0, ke, lA[bi], tid);
        else           stage512<32, AUXS>(xstep, D_SZ, m0, ke - 1024, lA[bi], tid);
      };
      auto sb = [&](int kt, int bi) {
        stage512<64, 0>(Wnt, 1280, nA, kt << 6, lB[bi], tid);
        stage512<64, 0>(Wnt, 1280, 512 + nA, kt << 6, lB[bi] + 64 * 64, tid);
      };
      auto cc = [&](int ai, int bi) {
#pragma unroll
        for (int kk = 0; kk < 2; ++kk) {
          short8 a = ldfrag(lA[ai], (rh << 4) + lr, (kk << 2) + lg);
          short8 b0 = ldfrag(lB[bi], cl, (kk << 2) + lg);          // mean
          short8 b1f = ldfrag(lB[bi], 64 + cl, (kk << 2) + lg);    // std
          acc0 = mfma16(a, b0, acc0);
          acc1 = mfma16(a, b1f, acc1);
        }
      };
      gloop<20, 2>(wv, sa, sb, cc);
      float bm = bn[col], bs = bn[512 + col];
#pragma unroll
      for (int r = 0; r < 4; ++r) {
        int row = row0 + r;
        float z = zreg[r];
        float hn = (1.f - z) * (acc0[r] + bm) + z * oreg[r];
        hreg[r] = hn;
        st_bf16(&hbf[(size_t)row * H_SZ + col], hn);
        float ns = fabsf(acc1[r] + bs);
        float sn = fabsf((1.f - z) * ns + z * sreg[r]);
        sreg[r] = sn;
        st_bf16(&hstdb[(size_t)row * H_SZ + col], sn);
      }
    }
    sbar_arrive(scnt);
    stage512<64, 0>(W1t, H_SZ, nA, 0, lB[0], tid);   // prestage next P1 B0..2
    stage512<64, 0>(W1t, H_SZ, nA, 64, lB[1], tid);
    stage512<64, 0>(W1t, H_SZ, nA, 128, lB[2], tid);
    sbar_wait(scnt, ++p);
  }
  // final output: register state -> global
#pragma unroll
  for (int r = 0; r < 4; ++r) {
    int row = row0 + r;
    hf[(size_t)row * H_SZ + col] = hreg[r];
    hstdf[(size_t)row * H_SZ + col] = sreg[r];
  }
}

// =============== prep: W[k][n] f32  ->  Wt[n][k] bf16 =====================
__global__ void k_wt(const float* __restrict__ W, __hip_bfloat16* __restrict__ Wt,
                     int K, int N, int ld) {
  size_t i = (size_t)blockIdx.x * 256 + threadIdx.x;
  if (i >= (size_t)K * N) return;
  int n = (int)(i / K), k = (int)(i % K);
  Wt[(size_t)n * ld + k] = __float2bfloat16(W[(size_t)k * N + n]);
}

extern "C" void kernel_launch(void* const* d_in, const int* in_sizes, int n_in,
                              void* d_out, int out_size, void* d_ws, size_t ws_size,
                              hipStream_t stream) {
  const float* x     = (const float*)d_in[0];
  const float* xtime = (const float*)d_in[1];
  const float* W1    = (const float*)d_in[2];
  const float* b1    = (const float*)d_in[3];
  const float* W2    = (const float*)d_in[4];
  const float* b2    = (const float*)d_in[5];
  const float* Wz    = (const float*)d_in[6];
  const float* bz    = (const float*)d_in[7];
  const float* Wr    = (const float*)d_in[8];
  const float* br    = (const float*)d_in[9];
  const float* Wn    = (const float*)d_in[10];
  const float* bn    = (const float*)d_in[11];

  char* p = (char*)d_ws;
  __hip_bfloat16* W1t   = (__hip_bfloat16*)(p + 0);
  __hip_bfloat16* W2t   = (__hip_bfloat16*)(p + 524288);
  __hip_bfloat16* Wzrt  = (__hip_bfloat16*)(p + 1048576);
  __hip_bfloat16* Wnt   = (__hip_bfloat16*)(p + 3670016);
  float*          hf    = (float*)(p + 6291456);
  float*          hstdf = (float*)(p + 8388608);
  __hip_bfloat16* hbf   = (__hip_bfloat16*)(p + 14680064);
  __hip_bfloat16* Ubf   = (__hip_bfloat16*)(p + 15728640);
  __hip_bfloat16* hodeb = (__hip_bfloat16*)(p + 16777216);
  __hip_bfloat16* hstdb = (__hip_bfloat16*)(p + 17825792);
  __hip_bfloat16* A4    = (__hip_bfloat16*)(p + 18874368);
  __hip_bfloat16* xstep = (__hip_bfloat16*)(p + 20971520);
  unsigned*       bar   = (unsigned*)(p + 21495808);

  hipMemsetAsync(hbf, 0, 1048576, stream);
  hipMemsetAsync(hstdb, 0, 1048576, stream);
  hipMemsetAsync(bar, 0, 8192, stream);

  k_wt<<<(512 * 512 + 255) / 256, 256, 0, stream>>>(W1, W1t, 512, 512, 512);
  k_wt<<<(512 * 512 + 255) / 256, 256, 0, stream>>>(W2, W2t, 512, 512, 512);
  k_wt<<<(1280 * 512 + 255) / 256, 256, 0, stream>>>(Wz, Wzrt, 1280, 512, 1280);
  k_wt<<<(1280 * 512 + 255) / 256, 256, 0, stream>>>(Wr, Wzrt + (size_t)512 * 1280, 1280, 512, 1280);
  k_wt<<<(1280 * 1024 + 255) / 256, 256, 0, stream>>>(Wn, Wnt, 1280, 1024, 1280);

  // persistent kernel: 256 blocks x 512 threads (1 block/CU) = 32 strips x 8
  // slices; strip-aligned barrier arrival (no cross-strip CU contention);
  // arrive -> prestage -> poll barrier split
  k_fused<<<NBLK, NTHR, 0, stream>>>(x, xtime, W1t, b1, W2t, b2, Wzrt, bz, br,
                                     Wnt, bn, hf, hstdf, hbf, Ubf,
                                     hodeb, hstdb, A4, xstep, bar);

  hipMemcpyAsync(d_out, hf, 2097152, hipMemcpyDeviceToDevice, stream);
  hipMemcpyAsync((char*)d_out + 2097152, hstdf, 2097152, hipMemcpyDeviceToDevice, stream);
}